// Round 6
// baseline (1342.215 us; speedup 1.0000x reference)
//
#include <hip/hip_runtime.h>

#define B_ 8
#define C_ 256
#define N_ 4096

typedef __attribute__((ext_vector_type(8))) __bf16 bf16x8;
typedef __attribute__((ext_vector_type(4))) float f32x4;

__device__ __forceinline__ unsigned short f2bf(float f) {
  union { float f; unsigned u; } v; v.f = f;
  unsigned r = v.u + 0x7fffu + ((v.u >> 16) & 1u);
  return (unsigned short)(r >> 16);
}

__device__ __forceinline__ uint4 pack8(const float* s) {
  uint4 o;
  o.x = (unsigned)f2bf(s[0]) | ((unsigned)f2bf(s[1]) << 16);
  o.y = (unsigned)f2bf(s[2]) | ((unsigned)f2bf(s[3]) << 16);
  o.z = (unsigned)f2bf(s[4]) | ((unsigned)f2bf(s[5]) << 16);
  o.w = (unsigned)f2bf(s[6]) | ((unsigned)f2bf(s[7]) << 16);
  return o;
}

// async global->LDS DMA, 16 B per lane; LDS dest = wave-uniform base + lane*16
__device__ __forceinline__ void dma16(const void* g, void* l) {
  __builtin_amdgcn_global_load_lds(
      (const __attribute__((address_space(1))) unsigned int*)(uintptr_t)g,
      (__attribute__((address_space(3))) unsigned int*)(uintptr_t)l, 16, 0, 0);
}

// ---------------------------------------------------------------------------
// Kernel 0: prep (round-5 proven). xT[b][n][c] = bf16(x[b][c][n]) + W -> bf16.
// Grid (64 ntiles, 4 ctiles, 8 b), 256 thr.
// ---------------------------------------------------------------------------
__global__ __launch_bounds__(256) void prep(
    const float* __restrict__ x,
    const float* __restrict__ Wq, const float* __restrict__ Wk,
    const float* __restrict__ Wv,
    unsigned short* __restrict__ xT, unsigned short* __restrict__ Wbf)
{
  __shared__ unsigned int xTl[64][33];
  const int t   = threadIdx.x;
  const int n0  = blockIdx.x * 64;
  const int ct0 = blockIdx.y * 64;
  const int b   = blockIdx.z;

  if (blockIdx.z == 0) {
    const int bid = blockIdx.x + 64 * blockIdx.y;
    if (bid < 96) {
      const int el0 = (bid * 256 + t) * 8;
      const int mat = el0 >> 16;
      const int off = el0 & 65535;
      const float* src = (mat == 0) ? Wq : (mat == 1) ? Wk : Wv;
      float tmp[8];
      float4 f0 = ((const float4*)(src + off))[0];
      float4 f1 = ((const float4*)(src + off))[1];
      tmp[0]=f0.x; tmp[1]=f0.y; tmp[2]=f0.z; tmp[3]=f0.w;
      tmp[4]=f1.x; tmp[5]=f1.y; tmp[6]=f1.z; tmp[7]=f1.w;
      *(uint4*)(Wbf + el0) = pack8(tmp);
    }
  }

  {
    const int cp = t >> 3;
    const int nq = t & 7;
    const float* s0 = x + ((size_t)(b * C_ + ct0 + 2*cp) * N_ + n0 + nq * 8);
    const float* s1 = s0 + N_;
    float4 a0 = ((const float4*)s0)[0], a1 = ((const float4*)s0)[1];
    float4 b0 = ((const float4*)s1)[0], b1 = ((const float4*)s1)[1];
    float lo[8] = {a0.x,a0.y,a0.z,a0.w,a1.x,a1.y,a1.z,a1.w};
    float hi[8] = {b0.x,b0.y,b0.z,b0.w,b1.x,b1.y,b1.z,b1.w};
    #pragma unroll
    for (int k = 0; k < 8; ++k)
      xTl[nq*8 + k][cp] = (unsigned)f2bf(lo[k]) | ((unsigned)f2bf(hi[k]) << 16);
  }
  __syncthreads();

  {
    const int n = t >> 2, cq = t & 3;
    unsigned int vals[8];
    #pragma unroll
    for (int g = 0; g < 8; ++g) vals[g] = xTl[n][cq*8 + g];
    uint4* dst = (uint4*)(xT + ((size_t)(b * N_ + n0 + n)) * C_ + ct0 + cq*16);
    dst[0] = make_uint4(vals[0], vals[1], vals[2], vals[3]);
    dst[1] = make_uint4(vals[4], vals[5], vals[6], vals[7]);
  }
}

// ---------------------------------------------------------------------------
// Kernel 1: QKV GEMM (round-5 proven, V j-interleave permuted).
// Grid (32 ntiles, 8 b, 3 mats), 256 thr.
// ---------------------------------------------------------------------------
__global__ __launch_bounds__(256, 2) void qkv_gemm(
    const unsigned short* __restrict__ xT, const unsigned short* __restrict__ Wbf,
    const float* __restrict__ bq, const float* __restrict__ bk,
    const float* __restrict__ bv,
    unsigned short* __restrict__ qT, unsigned short* __restrict__ kT,
    unsigned short* __restrict__ vW)
{
  __shared__ char smraw[49152];

  const int t    = threadIdx.x;
  const int lane = t & 63;
  const int w    = t >> 6;
  const int m16  = lane & 15;
  const int q    = (lane >> 4) & 3;
  const int nt0  = blockIdx.x * 128;
  const int b    = blockIdx.y;
  const int mat  = blockIdx.z;
  const size_t bN = (size_t)b * N_;

  const unsigned short* Wm = Wbf + mat * 65536;
  const float* bm = (mat == 0) ? bq : (mat == 1) ? bk : bv;
  unsigned short* outp = (mat == 0) ? qT : (mat == 1) ? kT : vW;

  auto stage = [&](int buf, int cs) {
    #pragma unroll
    for (int p = 0; p < 4; ++p) {
      const int row = 64 * w + 16 * p + (lane >> 2);
      const int g   = (lane & 3) ^ (row & 3);
      dma16(Wm + row * 256 + cs * 32 + g * 8,
            smraw + buf * 16384 + (64 * w + 16 * p) * 64);
    }
    #pragma unroll
    for (int p = 0; p < 2; ++p) {
      const int row = 32 * w + 16 * p + (lane >> 2);
      const int g   = (lane & 3) ^ (row & 3);
      dma16(xT + (bN + nt0 + row) * 256 + cs * 32 + g * 8,
            smraw + 32768 + buf * 8192 + (32 * w + 16 * p) * 64);
    }
  };

  stage(0, 0);

  float br[4][4];
  #pragma unroll
  for (int ob = 0; ob < 4; ++ob)
    #pragma unroll
    for (int r = 0; r < 4; ++r) br[ob][r] = bm[64*w + ob*16 + q*4 + r];

  f32x4 acc[4][8] = {};

  for (int cs = 0; cs < 8; ++cs) {
    asm volatile("s_waitcnt vmcnt(0)" ::: "memory");
    __syncthreads();
    if (cs + 1 < 8) stage((cs + 1) & 1, cs + 1);
    const int buf = cs & 1;
    const unsigned short* Wt = (const unsigned short*)(smraw + buf * 16384);
    const unsigned short* Xt = (const unsigned short*)(smraw + 32768 + buf * 8192);

    bf16x8 af[4], bf_[8];
    #pragma unroll
    for (int ob = 0; ob < 4; ++ob) {
      const int o = 64*w + ob*16 + m16;
      af[ob] = *(const bf16x8*)&Wt[o * 32 + ((q ^ (o & 3)) * 8)];
    }
    #pragma unroll
    for (int nb = 0; nb < 8; ++nb) {
      const int n = nb*16 + m16;
      bf_[nb] = *(const bf16x8*)&Xt[n * 32 + ((q ^ (n & 3)) * 8)];
    }
    #pragma unroll
    for (int ob = 0; ob < 4; ++ob)
      #pragma unroll
      for (int nb = 0; nb < 8; ++nb)
        acc[ob][nb] = __builtin_amdgcn_mfma_f32_16x16x32_bf16(af[ob], bf_[nb], acc[ob][nb], 0,0,0);
  }

  float* Dst = (float*)smraw;
  for (int nc = 0; nc < 4; ++nc) {
    __syncthreads();
    #pragma unroll
    for (int ob = 0; ob < 4; ++ob)
      #pragma unroll
      for (int h = 0; h < 2; ++h) {
        const int nb = nc*2 + h;
        #pragma unroll
        for (int r = 0; r < 4; ++r)
          Dst[(64*w + ob*16 + q*4 + r) * 36 + h*16 + m16] = acc[ob][nb][r] + br[ob][r];
      }
    __syncthreads();

    if (mat < 2) {
      const int n_loc = t & 31, oc = t >> 5;
      float vals[32];
      #pragma unroll
      for (int k = 0; k < 32; ++k) vals[k] = Dst[(oc*32 + k) * 36 + n_loc];
      uint4* dst = (uint4*)(outp + (bN + nt0 + nc*32 + n_loc) * C_ + oc*32);
      #pragma unroll
      for (int g = 0; g < 4; ++g) dst[g] = pack8(vals + g*8);
    } else {
      float vals[32], pv[32];
      #pragma unroll
      for (int k = 0; k < 32; ++k) vals[k] = Dst[t * 36 + k];
      #pragma unroll
      for (int p = 0; p < 32; ++p)
        pv[p] = vals[16*((p>>2)&1) + 4*(p>>3) + (p&3)];
      uint4* dst = (uint4*)(outp + ((size_t)(b * C_ + t)) * N_ + nt0 + nc*32);
      #pragma unroll
      for (int g = 0; g < 4; ++g) dst[g] = pack8(pv + g*8);
    }
  }
}

// ---------------------------------------------------------------------------
// Kernel 2: flash attention, in-block j-split.
// 512 thr = 8 waves = 2 teams x 4 waves. Team tm covers j in [tm*2048, +2048),
// each wave owns 32 i (2 groups of 16); i-tile 128. Fixed-max softmax (M0=64)
// => partials combine additively. End: teams swap half the c-range via LDS.
// LDS: per team double-buffered K(16K)+V(16K) = 128 KB. Grid (8 b, 32 itiles)
// = 256 blocks = 1/CU, 8 waves/CU = 2/SIMD.
// ---------------------------------------------------------------------------
__global__ __launch_bounds__(512, 2) void attn6(
    const unsigned short* __restrict__ qT, const unsigned short* __restrict__ kT,
    const unsigned short* __restrict__ vW, const float* __restrict__ x,
    const float* __restrict__ gamma, float* __restrict__ out)
{
  __shared__ char smem[131072];
  __shared__ float l_lds[2][4][2][16];   // [team][pair(wt)][g][m16]

  const int t    = threadIdx.x;
  const int lane = t & 63;
  const int w    = t >> 6;
  const int tm   = w >> 2;         // team
  const int wt   = w & 3;          // wave-in-team
  const int b    = blockIdx.x;
  const int i0   = blockIdx.y * 128;
  const int m16  = lane & 15;
  const int q    = (lane >> 4) & 3;
  const int q8   = q * 8;
  const size_t bN = (size_t)b * N_;
  const size_t bC = (size_t)b * C_;

  char* const Kb0 = smem + tm * 65536;            // [stage] 16 KB each
  char* const Vb0 = smem + tm * 65536 + 32768;    // [stage] 16 KB each
  const int jbase = tm * 2048;

  auto stage = [&](int buf, int j0) {
    char* Kd = Kb0 + buf * 16384;
    char* Vd = Vb0 + buf * 16384;
    #pragma unroll
    for (int p = 0; p < 4; ++p) {          // K: 32 rows x 32 granules, swz ^(j&7)
      const int row = 8*wt + 2*p + (lane >> 5);
      const int g   = (lane & 31) ^ (row & 7);
      dma16(kT + (bN + j0 + row) * C_ + g * 8, Kd + (8*wt + 2*p) * 512);
    }
    #pragma unroll
    for (int p = 0; p < 4; ++p) {          // V: 256 rows x 4 granules, swz ^((c>>1)&3)
      const int row = 64*wt + 16*p + (lane >> 2);
      const int g   = (lane & 3) ^ ((row >> 1) & 3);
      dma16(vW + (bC + row) * N_ + j0 + g * 8, Vd + (64*wt + 16*p) * 64);
    }
  };

  stage(0, jbase);

  // Q fragments resident: i = i0 + wt*32 + g*16 + m16
  bf16x8 qf[2][8];
  #pragma unroll
  for (int g = 0; g < 2; ++g) {
    const unsigned short* qbase = qT + ((bN + i0 + wt*32 + g*16 + m16) * C_ + q8);
    #pragma unroll
    for (int ks = 0; ks < 8; ++ks) qf[g][ks] = *(const bf16x8*)(qbase + ks*32);
  }

  float l_lane[2] = {0.0f, 0.0f};
  f32x4 Oacc[2][16] = {};   // [g][cb]; O^T col=i (lane&15), row=c (q*4+reg)

  for (int jt = 0; jt < 64; ++jt) {
    asm volatile("s_waitcnt vmcnt(0)" ::: "memory");
    __syncthreads();
    if (jt + 1 < 64) stage((jt + 1) & 1, jbase + (jt + 1) * 32);

    const unsigned short* Kt = (const unsigned short*)(Kb0 + (jt & 1) * 16384);
    const unsigned short* Vt = (const unsigned short*)(Vb0 + (jt & 1) * 16384);

    // --- S^T = K * Q^T : col=i, row j = jb*16 + q*4 + reg ---
    f32x4 st[2][2] = {};
    #pragma unroll
    for (int ks = 0; ks < 8; ++ks) {
      #pragma unroll
      for (int jb = 0; jb < 2; ++jb) {
        const int j = jb*16 + m16;
        bf16x8 a = *(const bf16x8*)&Kt[j * 256 + (((4*ks + q) ^ (j & 7)) * 8)];
        st[0][jb] = __builtin_amdgcn_mfma_f32_16x16x32_bf16(a, qf[0][ks], st[0][jb], 0,0,0);
        st[1][jb] = __builtin_amdgcn_mfma_f32_16x16x32_bf16(a, qf[1][ks], st[1][jb], 0,0,0);
      }
    }

    // --- fixed-max softmax: p = exp(S - 64) ---
    union { uint4 u; bf16x8 v; } pk[2];
    #pragma unroll
    for (int g = 0; g < 2; ++g) {
      float ps[2][4];
      #pragma unroll
      for (int jb = 0; jb < 2; ++jb)
        #pragma unroll
        for (int r = 0; r < 4; ++r) {
          const float p = __expf(st[g][jb][r] - 64.0f);
          ps[jb][r] = p;
          l_lane[g] += p;
        }
      pk[g].u.x = (unsigned)f2bf(ps[0][0]) | ((unsigned)f2bf(ps[0][1]) << 16);
      pk[g].u.y = (unsigned)f2bf(ps[0][2]) | ((unsigned)f2bf(ps[0][3]) << 16);
      pk[g].u.z = (unsigned)f2bf(ps[1][0]) | ((unsigned)f2bf(ps[1][1]) << 16);
      pk[g].u.w = (unsigned)f2bf(ps[1][2]) | ((unsigned)f2bf(ps[1][3]) << 16);
    }

    // --- O^T += V * P^T ; one b128 V fragment feeds both i-groups ---
    #pragma unroll
    for (int cb = 0; cb < 16; ++cb) {
      const int c = cb*16 + m16;
      bf16x8 vf = *(const bf16x8*)&Vt[c * 32 + ((q ^ ((c >> 1) & 3)) * 8)];
      Oacc[0][cb] = __builtin_amdgcn_mfma_f32_16x16x32_bf16(vf, pk[0].v, Oacc[0][cb], 0,0,0);
      Oacc[1][cb] = __builtin_amdgcn_mfma_f32_16x16x32_bf16(vf, pk[1].v, Oacc[1][cb], 0,0,0);
    }
  }

  // --- reduce l across q-groups (lanes m16, +16, +32, +48 hold same i) ---
  float l_mine[2];
  #pragma unroll
  for (int g = 0; g < 2; ++g) {
    float l = l_lane[g];
    l += __shfl_xor(l, 16);
    l += __shfl_xor(l, 32);
    l_mine[g] = l;
  }

  // --- cross-team combine: swap half the c-range through LDS ---
  asm volatile("s_waitcnt vmcnt(0)" ::: "memory");
  __syncthreads();   // all waves done with K/V LDS

  const int give0 = (tm == 0) ? 8 : 0;   // cb half we send away
  const int keep0 = (tm == 0) ? 0 : 8;   // cb half we keep & finalize
  float4* const xch = (float4*)smem;
  {
    float4* wr = xch + wt * 2048 + tm * 1024;   // pair region, my direction
    #pragma unroll
    for (int g = 0; g < 2; ++g)
      #pragma unroll
      for (int h = 0; h < 8; ++h) {
        const f32x4 o = Oacc[g][give0 + h];
        wr[(g*8 + h) * 64 + lane] = make_float4(o[0], o[1], o[2], o[3]);
      }
    if (q == 0) {
      l_lds[tm][wt][0][m16] = l_mine[0];
      l_lds[tm][wt][1][m16] = l_mine[1];
    }
  }
  __syncthreads();
  float l_tot[2];
  {
    const float4* rd = xch + wt * 2048 + (1 - tm) * 1024;
    #pragma unroll
    for (int g = 0; g < 2; ++g)
      #pragma unroll
      for (int h = 0; h < 8; ++h) {
        float4 v = rd[(g*8 + h) * 64 + lane];
        f32x4& o = Oacc[g][keep0 + h];
        o[0] += v.x; o[1] += v.y; o[2] += v.z; o[3] += v.w;
      }
    #pragma unroll
    for (int g = 0; g < 2; ++g)
      l_tot[g] = l_mine[g] + l_lds[1 - tm][wt][g][m16];
  }

  // --- epilogue: out[b][c][i] = gamma * O^T[c][i] / (l_i * 64) + x[b][c][i]
  //     team tm stores c in [tm*128, tm*128+128) ---
  const float gm = gamma[0];
  #pragma unroll
  for (int g = 0; g < 2; ++g) {
    const float fs = gm / (l_tot[g] * 64.0f);
    const int icol = i0 + wt*32 + g*16 + m16;
    #pragma unroll
    for (int h = 0; h < 8; ++h) {
      const int cb = keep0 + h;
      #pragma unroll
      for (int r = 0; r < 4; ++r) {
        const int c = cb*16 + q*4 + r;
        const size_t idx = (bC + c) * N_ + icol;
        out[idx] = Oacc[g][cb][r] * fs + x[idx];
      }
    }
  }
}

extern "C" void kernel_launch(void* const* d_in, const int* in_sizes, int n_in,
                              void* d_out, int out_size, void* d_ws, size_t ws_size,
                              hipStream_t stream) {
  const float* x     = (const float*)d_in[0];
  const float* Wq    = (const float*)d_in[1];
  const float* bq    = (const float*)d_in[2];
  const float* Wk    = (const float*)d_in[3];
  const float* bk    = (const float*)d_in[4];
  const float* Wv    = (const float*)d_in[5];
  const float* bv    = (const float*)d_in[6];
  const float* gamma = (const float*)d_in[7];
  float* out = (float*)d_out;

  unsigned short* xT  = (unsigned short*)d_ws;            // 16 MB
  unsigned short* Wbf = xT + (size_t)B_ * N_ * C_;        // 384 KB
  unsigned short* qT  = Wbf + 3 * 65536;                  // 16 MB
  unsigned short* kT  = qT + (size_t)B_ * N_ * C_;        // 16 MB
  unsigned short* vW  = kT + (size_t)B_ * N_ * C_;        // 16 MB

  prep<<<dim3(64, 4, 8), dim3(256), 0, stream>>>(x, Wq, Wk, Wv, xT, Wbf);
  qkv_gemm<<<dim3(32, 8, 3), dim3(256), 0, stream>>>(xT, Wbf, bq, bk, bv, qT, kT, vW);
  attn6<<<dim3(8, 32), dim3(512), 0, stream>>>(qT, kT, vW, x, gamma, out);
}

// Round 7
// 421.017 us; speedup vs baseline: 3.1880x; 3.1880x over previous
//
#include <hip/hip_runtime.h>

#define B_ 8
#define C_ 256
#define N_ 4096

typedef __attribute__((ext_vector_type(8))) __bf16 bf16x8;
typedef __attribute__((ext_vector_type(4))) float f32x4;

__device__ __forceinline__ unsigned short f2bf(float f) {
  union { float f; unsigned u; } v; v.f = f;
  unsigned r = v.u + 0x7fffu + ((v.u >> 16) & 1u);
  return (unsigned short)(r >> 16);
}

__device__ __forceinline__ float bf2f(unsigned short us) {
  union { unsigned u; float f; } v; v.u = ((unsigned)us) << 16;
  return v.f;
}

__device__ __forceinline__ uint4 pack8(const float* s) {
  uint4 o;
  o.x = (unsigned)f2bf(s[0]) | ((unsigned)f2bf(s[1]) << 16);
  o.y = (unsigned)f2bf(s[2]) | ((unsigned)f2bf(s[3]) << 16);
  o.z = (unsigned)f2bf(s[4]) | ((unsigned)f2bf(s[5]) << 16);
  o.w = (unsigned)f2bf(s[6]) | ((unsigned)f2bf(s[7]) << 16);
  return o;
}

// async global->LDS DMA, 16 B per lane; LDS dest = wave-uniform base + lane*16
__device__ __forceinline__ void dma16(const void* g, void* l) {
  __builtin_amdgcn_global_load_lds(
      (const __attribute__((address_space(1))) unsigned int*)(uintptr_t)g,
      (__attribute__((address_space(3))) unsigned int*)(uintptr_t)l, 16, 0, 0);
}

// ---------------------------------------------------------------------------
// Kernel 0: prep (round-5 proven) + zero the 256 pair-flags each launch.
// Grid (64 ntiles, 4 ctiles, 8 b), 256 thr.
// ---------------------------------------------------------------------------
__global__ __launch_bounds__(256) void prep(
    const float* __restrict__ x,
    const float* __restrict__ Wq, const float* __restrict__ Wk,
    const float* __restrict__ Wv,
    unsigned short* __restrict__ xT, unsigned short* __restrict__ Wbf,
    unsigned int* __restrict__ flags)
{
  __shared__ unsigned int xTl[64][33];
  const int t   = threadIdx.x;
  const int n0  = blockIdx.x * 64;
  const int ct0 = blockIdx.y * 64;
  const int b   = blockIdx.z;

  if (blockIdx.z == 0) {
    const int bid = blockIdx.x + 64 * blockIdx.y;
    if (bid == 255) flags[t] = 0u;          // zero 256 pair flags
    if (bid < 96) {
      const int el0 = (bid * 256 + t) * 8;
      const int mat = el0 >> 16;
      const int off = el0 & 65535;
      const float* src = (mat == 0) ? Wq : (mat == 1) ? Wk : Wv;
      float tmp[8];
      float4 f0 = ((const float4*)(src + off))[0];
      float4 f1 = ((const float4*)(src + off))[1];
      tmp[0]=f0.x; tmp[1]=f0.y; tmp[2]=f0.z; tmp[3]=f0.w;
      tmp[4]=f1.x; tmp[5]=f1.y; tmp[6]=f1.z; tmp[7]=f1.w;
      *(uint4*)(Wbf + el0) = pack8(tmp);
    }
  }

  {
    const int cp = t >> 3;
    const int nq = t & 7;
    const float* s0 = x + ((size_t)(b * C_ + ct0 + 2*cp) * N_ + n0 + nq * 8);
    const float* s1 = s0 + N_;
    float4 a0 = ((const float4*)s0)[0], a1 = ((const float4*)s0)[1];
    float4 b0 = ((const float4*)s1)[0], b1 = ((const float4*)s1)[1];
    float lo[8] = {a0.x,a0.y,a0.z,a0.w,a1.x,a1.y,a1.z,a1.w};
    float hi[8] = {b0.x,b0.y,b0.z,b0.w,b1.x,b1.y,b1.z,b1.w};
    #pragma unroll
    for (int k = 0; k < 8; ++k)
      xTl[nq*8 + k][cp] = (unsigned)f2bf(lo[k]) | ((unsigned)f2bf(hi[k]) << 16);
  }
  __syncthreads();

  {
    const int n = t >> 2, cq = t & 3;
    unsigned int vals[8];
    #pragma unroll
    for (int g = 0; g < 8; ++g) vals[g] = xTl[n][cq*8 + g];
    uint4* dst = (uint4*)(xT + ((size_t)(b * N_ + n0 + n)) * C_ + ct0 + cq*16);
    dst[0] = make_uint4(vals[0], vals[1], vals[2], vals[3]);
    dst[1] = make_uint4(vals[4], vals[5], vals[6], vals[7]);
  }
}

// ---------------------------------------------------------------------------
// Kernel 1: QKV GEMM (round-5 proven, V j-interleave permuted). Unchanged.
// Grid (32 ntiles, 8 b, 3 mats), 256 thr.
// ---------------------------------------------------------------------------
__global__ __launch_bounds__(256, 2) void qkv_gemm(
    const unsigned short* __restrict__ xT, const unsigned short* __restrict__ Wbf,
    const float* __restrict__ bq, const float* __restrict__ bk,
    const float* __restrict__ bv,
    unsigned short* __restrict__ qT, unsigned short* __restrict__ kT,
    unsigned short* __restrict__ vW)
{
  __shared__ char smraw[49152];

  const int t    = threadIdx.x;
  const int lane = t & 63;
  const int w    = t >> 6;
  const int m16  = lane & 15;
  const int q    = (lane >> 4) & 3;
  const int nt0  = blockIdx.x * 128;
  const int b    = blockIdx.y;
  const int mat  = blockIdx.z;
  const size_t bN = (size_t)b * N_;

  const unsigned short* Wm = Wbf + mat * 65536;
  const float* bm = (mat == 0) ? bq : (mat == 1) ? bk : bv;
  unsigned short* outp = (mat == 0) ? qT : (mat == 1) ? kT : vW;

  auto stage = [&](int buf, int cs) {
    #pragma unroll
    for (int p = 0; p < 4; ++p) {
      const int row = 64 * w + 16 * p + (lane >> 2);
      const int g   = (lane & 3) ^ (row & 3);
      dma16(Wm + row * 256 + cs * 32 + g * 8,
            smraw + buf * 16384 + (64 * w + 16 * p) * 64);
    }
    #pragma unroll
    for (int p = 0; p < 2; ++p) {
      const int row = 32 * w + 16 * p + (lane >> 2);
      const int g   = (lane & 3) ^ (row & 3);
      dma16(xT + (bN + nt0 + row) * 256 + cs * 32 + g * 8,
            smraw + 32768 + buf * 8192 + (32 * w + 16 * p) * 64);
    }
  };

  stage(0, 0);

  float br[4][4];
  #pragma unroll
  for (int ob = 0; ob < 4; ++ob)
    #pragma unroll
    for (int r = 0; r < 4; ++r) br[ob][r] = bm[64*w + ob*16 + q*4 + r];

  f32x4 acc[4][8] = {};

  for (int cs = 0; cs < 8; ++cs) {
    asm volatile("s_waitcnt vmcnt(0)" ::: "memory");
    __syncthreads();
    if (cs + 1 < 8) stage((cs + 1) & 1, cs + 1);
    const int buf = cs & 1;
    const unsigned short* Wt = (const unsigned short*)(smraw + buf * 16384);
    const unsigned short* Xt = (const unsigned short*)(smraw + 32768 + buf * 8192);

    bf16x8 af[4], bf_[8];
    #pragma unroll
    for (int ob = 0; ob < 4; ++ob) {
      const int o = 64*w + ob*16 + m16;
      af[ob] = *(const bf16x8*)&Wt[o * 32 + ((q ^ (o & 3)) * 8)];
    }
    #pragma unroll
    for (int nb = 0; nb < 8; ++nb) {
      const int n = nb*16 + m16;
      bf_[nb] = *(const bf16x8*)&Xt[n * 32 + ((q ^ (n & 3)) * 8)];
    }
    #pragma unroll
    for (int ob = 0; ob < 4; ++ob)
      #pragma unroll
      for (int nb = 0; nb < 8; ++nb)
        acc[ob][nb] = __builtin_amdgcn_mfma_f32_16x16x32_bf16(af[ob], bf_[nb], acc[ob][nb], 0,0,0);
  }

  float* Dst = (float*)smraw;
  for (int nc = 0; nc < 4; ++nc) {
    __syncthreads();
    #pragma unroll
    for (int ob = 0; ob < 4; ++ob)
      #pragma unroll
      for (int h = 0; h < 2; ++h) {
        const int nb = nc*2 + h;
        #pragma unroll
        for (int r = 0; r < 4; ++r)
          Dst[(64*w + ob*16 + q*4 + r) * 36 + h*16 + m16] = acc[ob][nb][r] + br[ob][r];
      }
    __syncthreads();

    if (mat < 2) {
      const int n_loc = t & 31, oc = t >> 5;
      float vals[32];
      #pragma unroll
      for (int k = 0; k < 32; ++k) vals[k] = Dst[(oc*32 + k) * 36 + n_loc];
      uint4* dst = (uint4*)(outp + (bN + nt0 + nc*32 + n_loc) * C_ + oc*32);
      #pragma unroll
      for (int g = 0; g < 4; ++g) dst[g] = pack8(vals + g*8);
    } else {
      float vals[32], pv[32];
      #pragma unroll
      for (int k = 0; k < 32; ++k) vals[k] = Dst[t * 36 + k];
      #pragma unroll
      for (int p = 0; p < 32; ++p)
        pv[p] = vals[16*((p>>2)&1) + 4*(p>>3) + (p&3)];
      uint4* dst = (uint4*)(outp + ((size_t)(b * C_ + t)) * N_ + nt0 + nc*32);
      #pragma unroll
      for (int g = 0; g < 4; ++g) dst[g] = pack8(pv + g*8);
    }
  }
}

// ---------------------------------------------------------------------------
// Kernel 2: flash attention, cross-block j-split.
// Grid (2 jh, 8 b, 32 itiles) = 512 blocks, 256 thr (4 waves).
// Wave owns 32 i (2 groups of 16); i-tile 128; j-tile 32 double-buffered
// (attn5-proven staging/swizzles); fixed-max softmax (M0=64) => partials
// combine additively. Pair protocol: first-arriver stores bf16 partial O +
// f32 l, release-publishes; second acquires, adds, does epilogue.
// launch_bounds(256,1): compiler allocates ~235 VGPR; HW fits 2 blocks/CU.
// ---------------------------------------------------------------------------
__global__ __launch_bounds__(256, 1) void attn7(
    const unsigned short* __restrict__ qT, const unsigned short* __restrict__ kT,
    const unsigned short* __restrict__ vW, const float* __restrict__ x,
    const float* __restrict__ gamma, float* __restrict__ out,
    unsigned short* __restrict__ Opart, float* __restrict__ lpart,
    unsigned int* __restrict__ flags)
{
  __shared__ unsigned short Kbuf[2][32 * 256];   // 16 KB each, swz ^(j&7)
  __shared__ unsigned short Vbuf[2][256 * 32];   // 16 KB each, swz ^((c>>1)&3)

  const int t    = threadIdx.x;
  const int lane = t & 63;
  const int w    = t >> 6;
  const int jh   = blockIdx.x;
  const int b    = blockIdx.y;
  const int it   = blockIdx.z;
  const int i0   = it * 128;
  const int m16  = lane & 15;
  const int q    = (lane >> 4) & 3;
  const int q8   = q * 8;
  const size_t bN = (size_t)b * N_;
  const size_t bC = (size_t)b * C_;
  const int jbase = jh * 2048;

  auto stage = [&](int buf, int j0) {
    #pragma unroll
    for (int p = 0; p < 4; ++p) {          // K: 32 rows x 32 granules
      const int row = 8*w + 2*p + (lane >> 5);
      const int g   = (lane & 31) ^ (row & 7);
      dma16(kT + (bN + j0 + row) * C_ + g * 8, &Kbuf[buf][(8*w + 2*p) * 256]);
    }
    #pragma unroll
    for (int p = 0; p < 4; ++p) {          // V: 256 rows x 4 granules
      const int row = 64*w + 16*p + (lane >> 2);
      const int g   = (lane & 3) ^ ((row >> 1) & 3);
      dma16(vW + (bC + row) * N_ + j0 + g * 8, &Vbuf[buf][(64*w + 16*p) * 32]);
    }
  };

  stage(0, jbase);

  // Q fragments resident: i = i0 + w*32 + g*16 + m16
  bf16x8 qf[2][8];
  #pragma unroll
  for (int g = 0; g < 2; ++g) {
    const unsigned short* qbase = qT + ((bN + i0 + w*32 + g*16 + m16) * C_ + q8);
    #pragma unroll
    for (int ks = 0; ks < 8; ++ks) qf[g][ks] = *(const bf16x8*)(qbase + ks*32);
  }

  float l_lane[2] = {0.0f, 0.0f};
  f32x4 Oacc[2][16] = {};   // [g][cb]; O^T col=i (lane&15), row=c (q*4+reg)

  for (int jt = 0; jt < 64; ++jt) {
    asm volatile("s_waitcnt vmcnt(0)" ::: "memory");
    __syncthreads();
    if (jt + 1 < 64) stage((jt + 1) & 1, jbase + (jt + 1) * 32);

    const unsigned short* Kt = Kbuf[jt & 1];
    const unsigned short* Vt = Vbuf[jt & 1];

    // --- S^T = K * Q^T : col=i, row j = jb*16 + q*4 + reg ---
    f32x4 st[2][2] = {};
    #pragma unroll
    for (int ks = 0; ks < 8; ++ks) {
      #pragma unroll
      for (int jb = 0; jb < 2; ++jb) {
        const int j = jb*16 + m16;
        bf16x8 a = *(const bf16x8*)&Kt[j * 256 + (((4*ks + q) ^ (j & 7)) * 8)];
        st[0][jb] = __builtin_amdgcn_mfma_f32_16x16x32_bf16(a, qf[0][ks], st[0][jb], 0,0,0);
        st[1][jb] = __builtin_amdgcn_mfma_f32_16x16x32_bf16(a, qf[1][ks], st[1][jb], 0,0,0);
      }
    }

    // --- fixed-max softmax: p = exp(S - 64) ---
    union { uint4 u; bf16x8 v; } pk[2];
    #pragma unroll
    for (int g = 0; g < 2; ++g) {
      float ps[2][4];
      #pragma unroll
      for (int jb = 0; jb < 2; ++jb)
        #pragma unroll
        for (int r = 0; r < 4; ++r) {
          const float p = __expf(st[g][jb][r] - 64.0f);
          ps[jb][r] = p;
          l_lane[g] += p;
        }
      pk[g].u.x = (unsigned)f2bf(ps[0][0]) | ((unsigned)f2bf(ps[0][1]) << 16);
      pk[g].u.y = (unsigned)f2bf(ps[0][2]) | ((unsigned)f2bf(ps[0][3]) << 16);
      pk[g].u.z = (unsigned)f2bf(ps[1][0]) | ((unsigned)f2bf(ps[1][1]) << 16);
      pk[g].u.w = (unsigned)f2bf(ps[1][2]) | ((unsigned)f2bf(ps[1][3]) << 16);
    }

    // --- O^T += V * P^T ; one b128 V fragment feeds both i-groups ---
    #pragma unroll
    for (int cb = 0; cb < 16; ++cb) {
      const int c = cb*16 + m16;
      bf16x8 vf = *(const bf16x8*)&Vt[c * 32 + ((q ^ ((c >> 1) & 3)) * 8)];
      Oacc[0][cb] = __builtin_amdgcn_mfma_f32_16x16x32_bf16(vf, pk[0].v, Oacc[0][cb], 0,0,0);
      Oacc[1][cb] = __builtin_amdgcn_mfma_f32_16x16x32_bf16(vf, pk[1].v, Oacc[1][cb], 0,0,0);
    }
  }

  // --- reduce l across q-groups (lanes m16,+16,+32,+48 hold same i) ---
  float l_mine[2];
  #pragma unroll
  for (int g = 0; g < 2; ++g) {
    float l = l_lane[g];
    l += __shfl_xor(l, 16);
    l += __shfl_xor(l, 32);
    l_mine[g] = l;
  }

  // --- pair combine protocol ---
  const int pair = b * 32 + it;
  __shared__ unsigned int s_ret;
  if (t == 0)
    s_ret = __hip_atomic_fetch_add(&flags[pair], 1u, __ATOMIC_ACQ_REL,
                                   __HIP_MEMORY_SCOPE_AGENT);
  __syncthreads();
  const unsigned int ret = s_ret;
  unsigned short* Op = Opart + (size_t)pair * 32768;   // [c 256][i_local 128]
  float* lp = lpart + pair * 128;

  if (ret == 0) {
    // first: store unscaled partial O (bf16) + l (f32), publish.
    #pragma unroll
    for (int g = 0; g < 2; ++g)
      #pragma unroll
      for (int cb = 0; cb < 16; ++cb)
        #pragma unroll
        for (int r = 0; r < 4; ++r) {
          const int c = cb*16 + q*4 + r;
          Op[c * 128 + w*32 + g*16 + m16] = f2bf(Oacc[g][cb][r]);
        }
    if (q == 0) {
      lp[w*32 + m16]      = l_mine[0];
      lp[w*32 + 16 + m16] = l_mine[1];
    }
    __syncthreads();
    if (t == 0) {
      __threadfence();
      __hip_atomic_fetch_add(&flags[pair], 1000u, __ATOMIC_RELEASE,
                             __HIP_MEMORY_SCOPE_AGENT);
    }
    return;
  }

  // second: wait for partner's publish, combine, epilogue.
  if (t == 0) {
    while (__hip_atomic_load(&flags[pair], __ATOMIC_ACQUIRE,
                             __HIP_MEMORY_SCOPE_AGENT) < 1001u)
      __builtin_amdgcn_s_sleep(8);
  }
  __syncthreads();

  float l_tot[2];
  #pragma unroll
  for (int g = 0; g < 2; ++g)
    l_tot[g] = l_mine[g] + lp[w*32 + g*16 + m16];

  #pragma unroll
  for (int g = 0; g < 2; ++g)
    #pragma unroll
    for (int cb = 0; cb < 16; ++cb)
      #pragma unroll
      for (int r = 0; r < 4; ++r) {
        const int c = cb*16 + q*4 + r;
        Oacc[g][cb][r] += bf2f(Op[c * 128 + w*32 + g*16 + m16]);
      }

  const float gm = gamma[0];
  #pragma unroll
  for (int g = 0; g < 2; ++g) {
    const float fs = gm / (l_tot[g] * 64.0f);
    const int icol = i0 + w*32 + g*16 + m16;
    #pragma unroll
    for (int cb = 0; cb < 16; ++cb) {
      #pragma unroll
      for (int r = 0; r < 4; ++r) {
        const int c = cb*16 + q*4 + r;
        const size_t idx = (bC + c) * N_ + icol;
        out[idx] = Oacc[g][cb][r] * fs + x[idx];
      }
    }
  }
}

extern "C" void kernel_launch(void* const* d_in, const int* in_sizes, int n_in,
                              void* d_out, int out_size, void* d_ws, size_t ws_size,
                              hipStream_t stream) {
  const float* x     = (const float*)d_in[0];
  const float* Wq    = (const float*)d_in[1];
  const float* bq    = (const float*)d_in[2];
  const float* Wk    = (const float*)d_in[3];
  const float* bk    = (const float*)d_in[4];
  const float* Wv    = (const float*)d_in[5];
  const float* bv    = (const float*)d_in[6];
  const float* gamma = (const float*)d_in[7];
  float* out = (float*)d_out;

  const size_t NC = (size_t)B_ * N_ * C_;                 // 8.39M els
  unsigned short* xT  = (unsigned short*)d_ws;            // 16.78 MB (reused as Opart)
  unsigned short* Wbf = xT + NC;                          // 384 KB
  unsigned short* qT  = Wbf + 3 * 65536;                  // 16.78 MB
  unsigned short* kT  = qT + NC;                          // 16.78 MB
  unsigned short* vW  = kT + NC;                          // 16.78 MB
  unsigned int*  flags = (unsigned int*)(vW + NC);        // 1 KB
  float*         lpart = (float*)(flags + 256);           // 128 KB
  unsigned short* Opart = xT;                             // alias (xT dead after qkv)

  prep<<<dim3(64, 4, 8), dim3(256), 0, stream>>>(x, Wq, Wk, Wv, xT, Wbf, flags);
  qkv_gemm<<<dim3(32, 8, 3), dim3(256), 0, stream>>>(xT, Wbf, bq, bk, bv, qT, kT, vW);
  attn7<<<dim3(2, 8, 32), dim3(256), 0, stream>>>(qT, kT, vW, x, gamma, out,
                                                  Opart, lpart, flags);
}